// Round 11
// baseline (170.377 us; speedup 1.0000x reference)
//
#include <hip/hip_runtime.h>
#include <hip/hip_bf16.h>
#include <math.h>

// Problem constants
#define Bb   4
#define Cc   128
#define Nn   4096          // 64*64 spatial
#define BN   (Bb * Nn)
#define HP   0.1f
#define EPSN 1e-10f
#define EPSM 0.001f

typedef __attribute__((ext_vector_type(8))) short short8;  // 8 bf16 = 4 VGPRs
typedef __attribute__((ext_vector_type(4))) float f32x4;   // MFMA accumulator

// Workspace layout (float offsets)
#define OFF_MPART 0                // [4][32][128] = 16384 (fully overwritten)
#define OFF_ACC   16384            // [B] = 4   (zeroed by k_mean each launch)
#define OFF_CNT   16388            // [1] uint  (zeroed by k_mean each launch)
#define OFF_PMAX  16392            // [64][B*N] = 1048576 (fully overwritten)
#define OFF_SSP   1064968          // [64][B*N] = 1048576 (fully overwritten)
#define OFF_FXN   2113544          // bf16 packed [B*N*C] = 1048576 floats
#define OFF_FYN   3162120          // bf16 packed [B*N*C]

// Packed fragment-major layout (per batch, element index):
//   pk(n,k) = (n>>4)*2048 + (k>>3)*128 + (n&15)*8 + (k&7)
// -> an MFMA A/B fragment load (16 rows x 8 ch) is one lane-linear 1 KB
//    global_load_dwordx4 (lane offset = (q*16+l15)*16 B). No gather, no LDS.

__device__ __forceinline__ ushort f2bf(float v)
{
    __hip_bfloat16 h = __float2bfloat16(v);
    return *(ushort*)&h;
}

// ---------------------------------------------------------------------------
// Kernel 1: per-(b,c,chunk) partial sums of feature_y over 128 spatial rows.
// No atomics (mpart fully overwritten). Also zeroes acc+cnt for k_partial.
__global__ void k_mean(const float* __restrict__ fy, float* __restrict__ mpart,
                       float* __restrict__ acc, unsigned int* __restrict__ cnt)
{
    if (blockIdx.x == 0 && threadIdx.x < 5) {
        if (threadIdx.x < 4) acc[threadIdx.x] = 0.f;
        else *cnt = 0u;
    }
    int b = blockIdx.x >> 5;
    int chunk = blockIdx.x & 31;
    int c = threadIdx.x;           // 128 threads, one per channel
    const float* p = fy + ((size_t)b * Nn + (size_t)chunk * 128) * Cc + c;
    float s = 0.f;
    for (int n = 0; n < 128; ++n) s += p[(size_t)n * Cc];
    mpart[blockIdx.x * 128 + c] = s;
}

// ---------------------------------------------------------------------------
// Kernel 2: reduce mean partials (LDS prologue), center, L2-normalize over C,
// emit bf16 in PACKED layout. Block = 16 rows; thread t: row r=t>>4, chunk c=t&15.
__global__ void k_norm(const float* __restrict__ fx, const float* __restrict__ fy,
                       const float* __restrict__ mpart,
                       ushort* __restrict__ fxn, ushort* __restrict__ fyn)
{
    __shared__ float smean[128];
    const int bn0 = blockIdx.x * 16;
    const int b = bn0 >> 12;
    const int t = threadIdx.x;

    if (t < 128) {
        float s = 0.f;
        #pragma unroll
        for (int k = 0; k < 32; ++k) s += mpart[(b * 32 + k) * 128 + t];
        smean[t] = s * (1.f / Nn);
    }
    __syncthreads();

    const int r = t >> 4, c = t & 15;
    const int row = bn0 + r;
    const float* px = fx + (size_t)row * Cc + c * 8;
    const float* py = fy + (size_t)row * Cc + c * 8;

    float xv[8], yv[8];
    float sx = 0.f, sy = 0.f;
    #pragma unroll
    for (int e = 0; e < 8; ++e) {
        float m = smean[c * 8 + e];
        float x = px[e] - m;
        float y = py[e] - m;
        xv[e] = x; yv[e] = y;
        sx += x * x; sy += y * y;
    }
    #pragma unroll
    for (int o = 1; o < 16; o <<= 1) {
        sx += __shfl_xor(sx, o);
        sy += __shfl_xor(sy, o);
    }
    float ix = 1.f / (sqrtf(sx) + EPSN);
    float iy = 1.f / (sqrtf(sy) + EPSN);

    size_t dst = (size_t)b * Nn * Cc
               + (size_t)((bn0 & (Nn - 1)) >> 4) * 2048 + c * 128 + r * 8;
    ushort ox[8], oy[8];
    #pragma unroll
    for (int e = 0; e < 8; ++e) {
        ox[e] = f2bf(xv[e] * ix);
        oy[e] = f2bf(yv[e] * iy);
    }
    *(short8*)&fxn[dst] = *(short8*)ox;
    *(short8*)&fyn[dst] = *(short8*)oy;
}

// ---------------------------------------------------------------------------
// MFMA core (r10 structure, best measured pass time): zero-LDS-tile GEMM,
// block (bx,my,b) = 128 n-rows x 4 m-tiles, 2x2 waves of 64x64. A-fragments
// (af) carried across the mt loop; acc born+dies per mt -> AGPRs (no-spill
// rule, r2/r7-r10). All fragment loads lane-linear 1 KB dwordx4 from the
// packed layout. Wave-local epilogue, 64 partials/row, no cross-wave combine.
// PASS 1: zero barriers. per-row per-(mt,wx) max -> pmax[z][b*N+row]
// PASS 2: prologue reduces 64 pmax partials -> {c0,c1} in LDS (one barrier);
//         per-row per-(mt,wx) sum exp(fma(dot,c1,c0)) -> ssp[z][...]
template <int PASS>
__global__ __launch_bounds__(256, 1) void k_gemm(
    const ushort* __restrict__ fxn, const ushort* __restrict__ fyn,
    float* __restrict__ pmax, float* __restrict__ ssp)
{
    __shared__ float2 sctv[128];           // PASS 2 only (1 KB)

    const int tid  = threadIdx.x;
    const int lane = tid & 63;
    const int w    = tid >> 6;
    const int wy = w >> 1, wx = w & 1;
    const int l15 = lane & 15, q = lane >> 4;
    const int n0 = blockIdx.x * 128;
    const int my = blockIdx.y;             // 0..7 -> m-tiles my*4 .. my*4+3
    const int b  = blockIdx.z;

    // PASS 2 prologue: ctv for this block's 128 rows.
    //   d = 1-maxdot; t = 1/(HP*(d+eps)); arg(dot) = dot*t + (d-1)*t
    if (PASS == 2) {
        if (tid < 128) {
            int row = b * Nn + n0 + tid;
            float g = -1e30f;
            #pragma unroll
            for (int z = 0; z < 64; ++z)
                g = fmaxf(g, pmax[(size_t)z * BN + row]);
            float d = 1.f - g;
            float t = 1.f / (HP * (d + EPSM));
            sctv[tid] = (float2){(d - 1.f) * t, t};
        }
        __syncthreads();
    }

    const ushort* pA = fxn + (size_t)b * Nn * Cc
                     + (size_t)((n0 + wy * 64) >> 4) * 2048 + q * 128 + l15 * 8;
    const ushort* pBb = fyn + (size_t)b * Nn * Cc + q * 128 + l15 * 8;

    // A fragments for the whole block: 16 lane-linear loads, carried in regs.
    short8 af[4][4];
    #pragma unroll
    for (int kt = 0; kt < 4; ++kt)
        #pragma unroll
        for (int i = 0; i < 4; ++i)
            af[kt][i] = *(const short8*)(pA + i * 2048 + kt * 512);

    #pragma unroll 1
    for (int mt = 0; mt < 4; ++mt) {
        const int m0 = (my * 4 + mt) * 128;
        const ushort* pB = pBb + (size_t)((m0 + wx * 64) >> 4) * 2048;

        f32x4 acc[4][4];
        #pragma unroll
        for (int i = 0; i < 4; ++i)
            #pragma unroll
            for (int j = 0; j < 4; ++j)
                acc[i][j] = (f32x4){0.f, 0.f, 0.f, 0.f};

        #pragma unroll
        for (int kt = 0; kt < 4; ++kt) {
            short8 bb[4];
            #pragma unroll
            for (int j = 0; j < 4; ++j)
                bb[j] = *(const short8*)(pB + j * 2048 + kt * 512);
            #pragma unroll
            for (int i = 0; i < 4; ++i)
                #pragma unroll
                for (int j = 0; j < 4; ++j)
                    acc[i][j] = __builtin_amdgcn_mfma_f32_16x16x32_bf16(
                        af[kt][i], bb[j], acc[i][j], 0, 0, 0);
        }

        // Wave-local epilogue. C/D: col = lane&15, row = (lane>>4)*4+reg [m89].
        const int z = (my * 4 + mt) * 2 + wx;
        float* dst = ((PASS == 1) ? pmax : ssp) + (size_t)z * BN + b * Nn
                   + n0 + wy * 64;
        #pragma unroll
        for (int i = 0; i < 4; ++i)
            #pragma unroll
            for (int r = 0; r < 4; ++r) {
                float v;
                if (PASS == 1) {
                    v = fmaxf(fmaxf(acc[i][0][r], acc[i][1][r]),
                              fmaxf(acc[i][2][r], acc[i][3][r]));
                    #pragma unroll
                    for (int o = 1; o < 16; o <<= 1)
                        v = fmaxf(v, __shfl_xor(v, o));
                } else {
                    float2 cc = sctv[wy * 64 + i * 16 + q * 4 + r]; // {c0,c1}
                    v = __expf(fmaf(acc[i][0][r], cc.y, cc.x))
                      + __expf(fmaf(acc[i][1][r], cc.y, cc.x))
                      + __expf(fmaf(acc[i][2][r], cc.y, cc.x))
                      + __expf(fmaf(acc[i][3][r], cc.y, cc.x));  // args <= ~0
                    #pragma unroll
                    for (int o = 1; o < 16; o <<= 1) v += __shfl_xor(v, o);
                }
                if (l15 == 0) dst[i * 16 + q * 4 + r] = v;
            }
    }
}

// ---------------------------------------------------------------------------
// Final: per-row 1/s, block-sum, atomicAdd per batch; the LAST block (device
// completion counter) computes out[b] = -log(acc[b]/N). 64 blocks, 256 thr.
__global__ void k_partial(const float* __restrict__ ssp, float* __restrict__ acc,
                          unsigned int* __restrict__ cnt, float* __restrict__ out)
{
    int i = blockIdx.x * 256 + threadIdx.x;   // 0 .. B*N-1
    float t = 0.f;
    #pragma unroll
    for (int z = 0; z < 64; ++z) t += ssp[(size_t)z * BN + i];
    float s = 1.f / t;
    #pragma unroll
    for (int o = 32; o > 0; o >>= 1) s += __shfl_xor(s, o);
    __shared__ float red[4];
    if ((threadIdx.x & 63) == 0) red[threadIdx.x >> 6] = s;
    __syncthreads();
    if (threadIdx.x == 0) {
        float bs = red[0] + red[1] + red[2] + red[3];
        atomicAdd(&acc[blockIdx.x >> 4], bs);     // 16 blocks per batch
        __threadfence();                          // acc adds visible device-wide
        unsigned int c = atomicAdd(cnt, 1u);
        if (c == 63u) {                           // last block finishes
            __threadfence();
            #pragma unroll
            for (int b2 = 0; b2 < Bb; ++b2) {
                float tb = atomicAdd(&acc[b2], 0.f);   // device-coherent read
                out[b2] = -logf(tb * (1.f / Nn));
            }
        }
    }
}

// ---------------------------------------------------------------------------
extern "C" void kernel_launch(void* const* d_in, const int* in_sizes, int n_in,
                              void* d_out, int out_size, void* d_ws, size_t ws_size,
                              hipStream_t stream)
{
    const float* fx = (const float*)d_in[0];
    const float* fy = (const float*)d_in[1];
    float* out = (float*)d_out;
    float* ws  = (float*)d_ws;

    float* mpart = ws + OFF_MPART;
    float* acc   = ws + OFF_ACC;
    unsigned int* cnt = (unsigned int*)(ws + OFF_CNT);
    float* pmax  = ws + OFF_PMAX;
    float* ssp   = ws + OFF_SSP;
    ushort* fxn  = (ushort*)(ws + OFF_FXN);
    ushort* fyn  = (ushort*)(ws + OFF_FYN);

    // 5 dispatches total (was 8): launch overhead was ~8 us/dispatch.
    k_mean<<<dim3(Bb * 32), dim3(128), 0, stream>>>(fy, mpart, acc, cnt);
    k_norm<<<dim3(BN / 16), dim3(256), 0, stream>>>(fx, fy, mpart, fxn, fyn);

    dim3 gg(32, 8, Bb);   // 1024 blocks, 4 m-tiles each
    k_gemm<1><<<gg, dim3(256), 0, stream>>>(fxn, fyn, pmax, nullptr);
    k_gemm<2><<<gg, dim3(256), 0, stream>>>(fxn, fyn, pmax, ssp);
    k_partial<<<dim3(64), dim3(256), 0, stream>>>(ssp, acc, cnt, out);
}

// Round 12
// 166.115 us; speedup vs baseline: 1.0257x; 1.0257x over previous
//
#include <hip/hip_runtime.h>
#include <hip/hip_bf16.h>
#include <math.h>

// Problem constants
#define Bb   4
#define Cc   128
#define Nn   4096          // 64*64 spatial
#define BN   (Bb * Nn)
#define HP   0.1f
#define EPSN 1e-10f
#define EPSM 0.001f

typedef __attribute__((ext_vector_type(8))) short short8;  // 8 bf16 = 4 VGPRs
typedef __attribute__((ext_vector_type(4))) float f32x4;   // MFMA accumulator

// Workspace layout (float offsets)
#define OFF_MPART 0                // [4][32][128] = 16384 (fully overwritten)
#define OFF_ACC   16384            // [B] = 4   (zeroed by k_mean each launch)
#define OFF_CNT   16388            // [1] uint  (zeroed by k_mean each launch)
#define OFF_PMAX  16392            // [64][B*N] = 1048576 (fully overwritten)
#define OFF_SSP   1064968          // [64][B*N] = 1048576 (fully overwritten)
#define OFF_FXN   2113544          // bf16 packed [B*N*C] = 1048576 floats
#define OFF_FYN   3162120          // bf16 packed [B*N*C]

// Packed fragment-major layout (per batch, element index):
//   pk(n,k) = (n>>4)*2048 + (k>>3)*128 + (n&15)*8 + (k&7)
// -> an MFMA A/B fragment load (16 rows x 8 ch) is one lane-linear 1 KB
//    global_load_dwordx4 (lane offset = (q*16+l15)*16 B). No gather, no LDS.

__device__ __forceinline__ ushort f2bf(float v)
{
    __hip_bfloat16 h = __float2bfloat16(v);
    return *(ushort*)&h;
}

// ---------------------------------------------------------------------------
// Kernel 1: per-(b,c,chunk) partial sums of feature_y over 128 spatial rows.
// No atomics (mpart fully overwritten). Also zeroes acc+cnt for k_partial.
__global__ void k_mean(const float* __restrict__ fy, float* __restrict__ mpart,
                       float* __restrict__ acc, unsigned int* __restrict__ cnt)
{
    if (blockIdx.x == 0 && threadIdx.x < 5) {
        if (threadIdx.x < 4) acc[threadIdx.x] = 0.f;
        else *cnt = 0u;
    }
    int b = blockIdx.x >> 5;
    int chunk = blockIdx.x & 31;
    int c = threadIdx.x;           // 128 threads, one per channel
    const float* p = fy + ((size_t)b * Nn + (size_t)chunk * 128) * Cc + c;
    float s = 0.f;
    for (int n = 0; n < 128; ++n) s += p[(size_t)n * Cc];
    mpart[blockIdx.x * 128 + c] = s;
}

// ---------------------------------------------------------------------------
// Kernel 2: reduce mean partials (LDS prologue), center, L2-normalize over C,
// emit bf16 in PACKED layout. Block = 16 rows; thread t: row r=t>>4, chunk c=t&15.
__global__ void k_norm(const float* __restrict__ fx, const float* __restrict__ fy,
                       const float* __restrict__ mpart,
                       ushort* __restrict__ fxn, ushort* __restrict__ fyn)
{
    __shared__ float smean[128];
    const int bn0 = blockIdx.x * 16;
    const int b = bn0 >> 12;
    const int t = threadIdx.x;

    if (t < 128) {
        float s = 0.f;
        #pragma unroll
        for (int k = 0; k < 32; ++k) s += mpart[(b * 32 + k) * 128 + t];
        smean[t] = s * (1.f / Nn);
    }
    __syncthreads();

    const int r = t >> 4, c = t & 15;
    const int row = bn0 + r;
    const float* px = fx + (size_t)row * Cc + c * 8;
    const float* py = fy + (size_t)row * Cc + c * 8;

    float xv[8], yv[8];
    float sx = 0.f, sy = 0.f;
    #pragma unroll
    for (int e = 0; e < 8; ++e) {
        float m = smean[c * 8 + e];
        float x = px[e] - m;
        float y = py[e] - m;
        xv[e] = x; yv[e] = y;
        sx += x * x; sy += y * y;
    }
    #pragma unroll
    for (int o = 1; o < 16; o <<= 1) {
        sx += __shfl_xor(sx, o);
        sy += __shfl_xor(sy, o);
    }
    float ix = 1.f / (sqrtf(sx) + EPSN);
    float iy = 1.f / (sqrtf(sy) + EPSN);

    size_t dst = (size_t)b * Nn * Cc
               + (size_t)((bn0 & (Nn - 1)) >> 4) * 2048 + c * 128 + r * 8;
    ushort ox[8], oy[8];
    #pragma unroll
    for (int e = 0; e < 8; ++e) {
        ox[e] = f2bf(xv[e] * ix);
        oy[e] = f2bf(yv[e] * iy);
    }
    *(short8*)&fxn[dst] = *(short8*)ox;
    *(short8*)&fyn[dst] = *(short8*)oy;
}

// ---------------------------------------------------------------------------
// MFMA core (r10/r11 structure — best measured pass time) + XCD-AWARE SWIZZLE.
// Blocks dispatch round-robin across the 8 XCDs; without pinning, every XCD
// streams the full 8 MB (fxn+fyn, all batches) through its private 4 MB L2 ->
// capacity misses -> L3 latency (~2x L2) on every fragment load. Swizzle:
// xcd = idx&7, batch b = xcd>>1 -> each batch's 2 MB working set lives in one
// XCD pair's L2. Mapping is a speed heuristic only; correctness unaffected.
// Zero-LDS-tile GEMM, block = 128 n-rows x 4 m-tiles, 2x2 waves of 64x64;
// af carried across mt loop; acc born+dies per mt -> AGPRs (no-spill rule).
// PASS 1: per-row per-(mt,wx) max -> pmax[z][b*N+row], z=(my*4+mt)*2+wx
// PASS 2: prologue reduces 64 pmax partials -> {c0,c1} in LDS (one barrier);
//         per-row per-(mt,wx) sum exp(fma(dot,c1,c0)) -> ssp[z][...]
template <int PASS>
__global__ __launch_bounds__(256, 1) void k_gemm(
    const ushort* __restrict__ fxn, const ushort* __restrict__ fyn,
    float* __restrict__ pmax, float* __restrict__ ssp)
{
    __shared__ float2 sctv[128];           // PASS 2 only (1 KB)

    const int idx = blockIdx.x;
    const int xcd = idx & 7;
    const int b   = xcd >> 1;                          // batch pinned to XCD pair
    const int t8  = ((idx >> 3) << 1) | (xcd & 1);     // 0..255 unique per batch
    const int n0  = (t8 & 31) * 128;                   // n-tile
    const int my  = t8 >> 5;                           // 0..7 m-group

    const int tid  = threadIdx.x;
    const int lane = tid & 63;
    const int w    = tid >> 6;
    const int wy = w >> 1, wx = w & 1;
    const int l15 = lane & 15, q = lane >> 4;

    // PASS 2 prologue: ctv for this block's 128 rows.
    //   d = 1-maxdot; t = 1/(HP*(d+eps)); arg(dot) = dot*t + (d-1)*t
    if (PASS == 2) {
        if (tid < 128) {
            int row = b * Nn + n0 + tid;
            float g = -1e30f;
            #pragma unroll
            for (int z = 0; z < 64; ++z)
                g = fmaxf(g, pmax[(size_t)z * BN + row]);
            float d = 1.f - g;
            float t = 1.f / (HP * (d + EPSM));
            sctv[tid] = (float2){(d - 1.f) * t, t};
        }
        __syncthreads();
    }

    const ushort* pA = fxn + (size_t)b * Nn * Cc
                     + (size_t)((n0 + wy * 64) >> 4) * 2048 + q * 128 + l15 * 8;
    const ushort* pBb = fyn + (size_t)b * Nn * Cc + q * 128 + l15 * 8;

    // A fragments for the whole block: 16 lane-linear loads, carried in regs.
    short8 af[4][4];
    #pragma unroll
    for (int kt = 0; kt < 4; ++kt)
        #pragma unroll
        for (int i = 0; i < 4; ++i)
            af[kt][i] = *(const short8*)(pA + i * 2048 + kt * 512);

    #pragma unroll 1
    for (int mt = 0; mt < 4; ++mt) {
        const int m0 = (my * 4 + mt) * 128;
        const ushort* pB = pBb + (size_t)((m0 + wx * 64) >> 4) * 2048;

        f32x4 acc[4][4];
        #pragma unroll
        for (int i = 0; i < 4; ++i)
            #pragma unroll
            for (int j = 0; j < 4; ++j)
                acc[i][j] = (f32x4){0.f, 0.f, 0.f, 0.f};

        #pragma unroll
        for (int kt = 0; kt < 4; ++kt) {
            short8 bb[4];
            #pragma unroll
            for (int j = 0; j < 4; ++j)
                bb[j] = *(const short8*)(pB + j * 2048 + kt * 512);
            #pragma unroll
            for (int i = 0; i < 4; ++i)
                #pragma unroll
                for (int j = 0; j < 4; ++j)
                    acc[i][j] = __builtin_amdgcn_mfma_f32_16x16x32_bf16(
                        af[kt][i], bb[j], acc[i][j], 0, 0, 0);
        }

        // Wave-local epilogue. C/D: col = lane&15, row = (lane>>4)*4+reg [m89].
        const int z = (my * 4 + mt) * 2 + wx;
        float* dst = ((PASS == 1) ? pmax : ssp) + (size_t)z * BN + b * Nn
                   + n0 + wy * 64;
        #pragma unroll
        for (int i = 0; i < 4; ++i)
            #pragma unroll
            for (int r = 0; r < 4; ++r) {
                float v;
                if (PASS == 1) {
                    v = fmaxf(fmaxf(acc[i][0][r], acc[i][1][r]),
                              fmaxf(acc[i][2][r], acc[i][3][r]));
                    #pragma unroll
                    for (int o = 1; o < 16; o <<= 1)
                        v = fmaxf(v, __shfl_xor(v, o));
                } else {
                    float2 cc = sctv[wy * 64 + i * 16 + q * 4 + r]; // {c0,c1}
                    v = __expf(fmaf(acc[i][0][r], cc.y, cc.x))
                      + __expf(fmaf(acc[i][1][r], cc.y, cc.x))
                      + __expf(fmaf(acc[i][2][r], cc.y, cc.x))
                      + __expf(fmaf(acc[i][3][r], cc.y, cc.x));  // args <= ~0
                    #pragma unroll
                    for (int o = 1; o < 16; o <<= 1) v += __shfl_xor(v, o);
                }
                if (l15 == 0) dst[i * 16 + q * 4 + r] = v;
            }
    }
}

// ---------------------------------------------------------------------------
// Final: per-row 1/s, block-sum, atomicAdd per batch; the LAST block (device
// completion counter) computes out[b] = -log(acc[b]/N). 64 blocks, 256 thr.
__global__ void k_partial(const float* __restrict__ ssp, float* __restrict__ acc,
                          unsigned int* __restrict__ cnt, float* __restrict__ out)
{
    int i = blockIdx.x * 256 + threadIdx.x;   // 0 .. B*N-1
    float t = 0.f;
    #pragma unroll
    for (int z = 0; z < 64; ++z) t += ssp[(size_t)z * BN + i];
    float s = 1.f / t;
    #pragma unroll
    for (int o = 32; o > 0; o >>= 1) s += __shfl_xor(s, o);
    __shared__ float red[4];
    if ((threadIdx.x & 63) == 0) red[threadIdx.x >> 6] = s;
    __syncthreads();
    if (threadIdx.x == 0) {
        float bs = red[0] + red[1] + red[2] + red[3];
        atomicAdd(&acc[blockIdx.x >> 4], bs);     // 16 blocks per batch
        __threadfence();                          // acc adds visible device-wide
        unsigned int c = atomicAdd(cnt, 1u);
        if (c == 63u) {                           // last block finishes
            __threadfence();
            #pragma unroll
            for (int b2 = 0; b2 < Bb; ++b2) {
                float tb = atomicAdd(&acc[b2], 0.f);   // device-coherent read
                out[b2] = -logf(tb * (1.f / Nn));
            }
        }
    }
}

// ---------------------------------------------------------------------------
extern "C" void kernel_launch(void* const* d_in, const int* in_sizes, int n_in,
                              void* d_out, int out_size, void* d_ws, size_t ws_size,
                              hipStream_t stream)
{
    const float* fx = (const float*)d_in[0];
    const float* fy = (const float*)d_in[1];
    float* out = (float*)d_out;
    float* ws  = (float*)d_ws;

    float* mpart = ws + OFF_MPART;
    float* acc   = ws + OFF_ACC;
    unsigned int* cnt = (unsigned int*)(ws + OFF_CNT);
    float* pmax  = ws + OFF_PMAX;
    float* ssp   = ws + OFF_SSP;
    ushort* fxn  = (ushort*)(ws + OFF_FXN);
    ushort* fyn  = (ushort*)(ws + OFF_FYN);

    k_mean<<<dim3(Bb * 32), dim3(128), 0, stream>>>(fy, mpart, acc, cnt);
    k_norm<<<dim3(BN / 16), dim3(256), 0, stream>>>(fx, fy, mpart, fxn, fyn);

    // 1D grid, XCD-swizzled inside the kernel (batch pinned to XCD pair)
    k_gemm<1><<<dim3(1024), dim3(256), 0, stream>>>(fxn, fyn, pmax, nullptr);
    k_gemm<2><<<dim3(1024), dim3(256), 0, stream>>>(fxn, fyn, pmax, ssp);
    k_partial<<<dim3(64), dim3(256), 0, stream>>>(ssp, acc, cnt, out);
}

// Round 13
// 160.047 us; speedup vs baseline: 1.0645x; 1.0379x over previous
//
#include <hip/hip_runtime.h>
#include <hip/hip_bf16.h>
#include <math.h>

// Problem constants
#define Bb   4
#define Cc   128
#define Nn   4096          // 64*64 spatial
#define BN   (Bb * Nn)
#define HP   0.1f
#define EPSN 1e-10f
#define EPSM 0.001f

typedef __attribute__((ext_vector_type(8))) short short8;  // 8 bf16 = 4 VGPRs
typedef __attribute__((ext_vector_type(4))) float f32x4;   // MFMA accumulator

// Workspace layout (float offsets)
#define OFF_MPART 0                // [4][32][128] = 16384 (fully overwritten)
#define OFF_ACC   16384            // [B] = 4   (zeroed by k_mean each launch)
#define OFF_CNT   16388            // [1] uint  (zeroed by k_mean each launch)
#define OFF_PMAX  16392            // [64][B*N] = 1048576 (fully overwritten)
#define OFF_SSP   1064968          // [64][B*N] = 1048576 (fully overwritten)
#define OFF_FXN   2113544          // bf16 packed [B*N*C] = 1048576 floats
#define OFF_FYN   3162120          // bf16 packed [B*N*C]

// Packed fragment-major layout (per batch, element index):
//   pk(n,k) = (n>>4)*2048 + (k>>3)*128 + (n&15)*8 + (k&7)
// -> an MFMA A/B fragment load (16 rows x 8 ch) is one lane-linear 1 KB
//    global_load_dwordx4 (lane offset = (q*16+l15)*16 B). No gather, no LDS.

__device__ __forceinline__ ushort f2bf(float v)
{
    __hip_bfloat16 h = __float2bfloat16(v);
    return *(ushort*)&h;
}

// ---------------------------------------------------------------------------
// Kernel 1: per-(b,c,chunk) partial sums of feature_y over 128 spatial rows.
// No atomics (mpart fully overwritten). Also zeroes acc+cnt for k_partial.
__global__ void k_mean(const float* __restrict__ fy, float* __restrict__ mpart,
                       float* __restrict__ acc, unsigned int* __restrict__ cnt)
{
    if (blockIdx.x == 0 && threadIdx.x < 5) {
        if (threadIdx.x < 4) acc[threadIdx.x] = 0.f;
        else *cnt = 0u;
    }
    int b = blockIdx.x >> 5;
    int chunk = blockIdx.x & 31;
    int c = threadIdx.x;           // 128 threads, one per channel
    const float* p = fy + ((size_t)b * Nn + (size_t)chunk * 128) * Cc + c;
    float s = 0.f;
    for (int n = 0; n < 128; ++n) s += p[(size_t)n * Cc];
    mpart[blockIdx.x * 128 + c] = s;
}

// ---------------------------------------------------------------------------
// Kernel 2: reduce mean partials (LDS prologue), center, L2-normalize over C,
// emit bf16 in PACKED layout. Block = 16 rows; thread t: row r=t>>4, chunk c=t&15.
__global__ void k_norm(const float* __restrict__ fx, const float* __restrict__ fy,
                       const float* __restrict__ mpart,
                       ushort* __restrict__ fxn, ushort* __restrict__ fyn)
{
    __shared__ float smean[128];
    const int bn0 = blockIdx.x * 16;
    const int b = bn0 >> 12;
    const int t = threadIdx.x;

    if (t < 128) {
        float s = 0.f;
        #pragma unroll
        for (int k = 0; k < 32; ++k) s += mpart[(b * 32 + k) * 128 + t];
        smean[t] = s * (1.f / Nn);
    }
    __syncthreads();

    const int r = t >> 4, c = t & 15;
    const int row = bn0 + r;
    const float* px = fx + (size_t)row * Cc + c * 8;
    const float* py = fy + (size_t)row * Cc + c * 8;

    float xv[8], yv[8];
    float sx = 0.f, sy = 0.f;
    #pragma unroll
    for (int e = 0; e < 8; ++e) {
        float m = smean[c * 8 + e];
        float x = px[e] - m;
        float y = py[e] - m;
        xv[e] = x; yv[e] = y;
        sx += x * x; sy += y * y;
    }
    #pragma unroll
    for (int o = 1; o < 16; o <<= 1) {
        sx += __shfl_xor(sx, o);
        sy += __shfl_xor(sy, o);
    }
    float ix = 1.f / (sqrtf(sx) + EPSN);
    float iy = 1.f / (sqrtf(sy) + EPSN);

    size_t dst = (size_t)b * Nn * Cc
               + (size_t)((bn0 & (Nn - 1)) >> 4) * 2048 + c * 128 + r * 8;
    ushort ox[8], oy[8];
    #pragma unroll
    for (int e = 0; e < 8; ++e) {
        ox[e] = f2bf(xv[e] * ix);
        oy[e] = f2bf(yv[e] * iy);
    }
    *(short8*)&fxn[dst] = *(short8*)ox;
    *(short8*)&fyn[dst] = *(short8*)oy;
}

// ---------------------------------------------------------------------------
// MFMA core, OCCUPANCY EDITION. r10-r12 allocated ~188 regs/wave (124 VGPR +
// 64 AGPR) -> 2 waves/SIMD; every stall had one partner wave. This version:
// 512-thread blocks (8 waves), each wave a 32x64 subtile (2x4 MFMA grid):
// af 32 VGPR + acc 32 AGPR + ~55 misc -> ~120 regs/wave -> 4 waves/SIMD,
// 16 waves/CU (2x latency-hiding). Same total MFMA, same packed lane-linear
// loads, acc born+dies per mt (no-spill rule), zero LDS tiles, XCD pinning.
// Block: 128 n-rows x 8 m-tiles. Waves: wy=w>>1 (row group of 32), wx=w&1.
// PASS 1: per-row per-(mt,wx) max -> pmax[z][b*N+row], z=(my*8+mt)*2+wx
// PASS 2: prologue reduces 64 pmax partials -> {c0,c1} in LDS (one barrier);
//         per-row per-(mt,wx) sum exp(fma(dot,c1,c0)) -> ssp[z][...]
template <int PASS>
__global__ __launch_bounds__(512, 1) void k_gemm(
    const ushort* __restrict__ fxn, const ushort* __restrict__ fyn,
    float* __restrict__ pmax, float* __restrict__ ssp)
{
    __shared__ float2 sctv[128];           // PASS 2 only (1 KB)

    const int idx = blockIdx.x;            // 0..511
    const int xcd = idx & 7;
    const int b   = xcd >> 1;                          // batch pinned to XCD pair
    const int t7  = ((idx >> 3) << 1) | (xcd & 1);     // 0..127 unique per batch
    const int n0  = (t7 & 31) * 128;                   // n-tile
    const int my  = t7 >> 5;                           // 0..3 m-group (8 mt each)

    const int tid  = threadIdx.x;
    const int lane = tid & 63;
    const int w    = tid >> 6;             // 0..7
    const int wy = w >> 1, wx = w & 1;     // wy: 32-row group; wx: 64-col group
    const int l15 = lane & 15, q = lane >> 4;

    // PASS 2 prologue: ctv for this block's 128 rows.
    //   d = 1-maxdot; t = 1/(HP*(d+eps)); arg(dot) = dot*t + (d-1)*t
    if (PASS == 2) {
        if (tid < 128) {
            int row = b * Nn + n0 + tid;
            float g = -1e30f;
            #pragma unroll
            for (int z = 0; z < 64; ++z)
                g = fmaxf(g, pmax[(size_t)z * BN + row]);
            float d = 1.f - g;
            float t = 1.f / (HP * (d + EPSM));
            sctv[tid] = (float2){(d - 1.f) * t, t};
        }
        __syncthreads();
    }

    const ushort* pA = fxn + (size_t)b * Nn * Cc
                     + (size_t)((n0 + wy * 32) >> 4) * 2048 + q * 128 + l15 * 8;
    const ushort* pBb = fyn + (size_t)b * Nn * Cc + q * 128 + l15 * 8;

    // A fragments for the whole block: 8 lane-linear loads, carried in regs.
    short8 af[4][2];
    #pragma unroll
    for (int kt = 0; kt < 4; ++kt)
        #pragma unroll
        for (int i = 0; i < 2; ++i)
            af[kt][i] = *(const short8*)(pA + i * 2048 + kt * 512);

    #pragma unroll 1
    for (int mt = 0; mt < 8; ++mt) {
        const int m0 = (my * 8 + mt) * 128;
        const ushort* pB = pBb + (size_t)((m0 + wx * 64) >> 4) * 2048;

        f32x4 acc[2][4];
        #pragma unroll
        for (int i = 0; i < 2; ++i)
            #pragma unroll
            for (int j = 0; j < 4; ++j)
                acc[i][j] = (f32x4){0.f, 0.f, 0.f, 0.f};

        #pragma unroll
        for (int kt = 0; kt < 4; ++kt) {
            short8 bb[4];
            #pragma unroll
            for (int j = 0; j < 4; ++j)
                bb[j] = *(const short8*)(pB + j * 2048 + kt * 512);
            #pragma unroll
            for (int i = 0; i < 2; ++i)
                #pragma unroll
                for (int j = 0; j < 4; ++j)
                    acc[i][j] = __builtin_amdgcn_mfma_f32_16x16x32_bf16(
                        af[kt][i], bb[j], acc[i][j], 0, 0, 0);
        }

        // Wave-local epilogue. C/D: col = lane&15, row = (lane>>4)*4+reg [m89].
        const int z = (my * 8 + mt) * 2 + wx;
        float* dst = ((PASS == 1) ? pmax : ssp) + (size_t)z * BN + b * Nn
                   + n0 + wy * 32;
        #pragma unroll
        for (int i = 0; i < 2; ++i)
            #pragma unroll
            for (int r = 0; r < 4; ++r) {
                float v;
                if (PASS == 1) {
                    v = fmaxf(fmaxf(acc[i][0][r], acc[i][1][r]),
                              fmaxf(acc[i][2][r], acc[i][3][r]));
                    #pragma unroll
                    for (int o = 1; o < 16; o <<= 1)
                        v = fmaxf(v, __shfl_xor(v, o));
                } else {
                    float2 cc = sctv[wy * 32 + i * 16 + q * 4 + r]; // {c0,c1}
                    v = __expf(fmaf(acc[i][0][r], cc.y, cc.x))
                      + __expf(fmaf(acc[i][1][r], cc.y, cc.x))
                      + __expf(fmaf(acc[i][2][r], cc.y, cc.x))
                      + __expf(fmaf(acc[i][3][r], cc.y, cc.x));  // args <= ~0
                    #pragma unroll
                    for (int o = 1; o < 16; o <<= 1) v += __shfl_xor(v, o);
                }
                if (l15 == 0) dst[i * 16 + q * 4 + r] = v;
            }
    }
}

// ---------------------------------------------------------------------------
// Final: per-row 1/s, block-sum, atomicAdd per batch; the LAST block (device
// completion counter) computes out[b] = -log(acc[b]/N). 64 blocks, 256 thr.
__global__ void k_partial(const float* __restrict__ ssp, float* __restrict__ acc,
                          unsigned int* __restrict__ cnt, float* __restrict__ out)
{
    int i = blockIdx.x * 256 + threadIdx.x;   // 0 .. B*N-1
    float t = 0.f;
    #pragma unroll
    for (int z = 0; z < 64; ++z) t += ssp[(size_t)z * BN + i];
    float s = 1.f / t;
    #pragma unroll
    for (int o = 32; o > 0; o >>= 1) s += __shfl_xor(s, o);
    __shared__ float red[4];
    if ((threadIdx.x & 63) == 0) red[threadIdx.x >> 6] = s;
    __syncthreads();
    if (threadIdx.x == 0) {
        float bs = red[0] + red[1] + red[2] + red[3];
        atomicAdd(&acc[blockIdx.x >> 4], bs);     // 16 blocks per batch
        __threadfence();                          // acc adds visible device-wide
        unsigned int c = atomicAdd(cnt, 1u);
        if (c == 63u) {                           // last block finishes
            __threadfence();
            #pragma unroll
            for (int b2 = 0; b2 < Bb; ++b2) {
                float tb = atomicAdd(&acc[b2], 0.f);   // device-coherent read
                out[b2] = -logf(tb * (1.f / Nn));
            }
        }
    }
}

// ---------------------------------------------------------------------------
extern "C" void kernel_launch(void* const* d_in, const int* in_sizes, int n_in,
                              void* d_out, int out_size, void* d_ws, size_t ws_size,
                              hipStream_t stream)
{
    const float* fx = (const float*)d_in[0];
    const float* fy = (const float*)d_in[1];
    float* out = (float*)d_out;
    float* ws  = (float*)d_ws;

    float* mpart = ws + OFF_MPART;
    float* acc   = ws + OFF_ACC;
    unsigned int* cnt = (unsigned int*)(ws + OFF_CNT);
    float* pmax  = ws + OFF_PMAX;
    float* ssp   = ws + OFF_SSP;
    ushort* fxn  = (ushort*)(ws + OFF_FXN);
    ushort* fyn  = (ushort*)(ws + OFF_FYN);

    k_mean<<<dim3(Bb * 32), dim3(128), 0, stream>>>(fy, mpart, acc, cnt);
    k_norm<<<dim3(BN / 16), dim3(256), 0, stream>>>(fx, fy, mpart, fxn, fyn);

    // 512 blocks x 512 threads; XCD-pinned; 8 m-tiles per block
    k_gemm<1><<<dim3(512), dim3(512), 0, stream>>>(fxn, fyn, pmax, nullptr);
    k_gemm<2><<<dim3(512), dim3(512), 0, stream>>>(fxn, fyn, pmax, ssp);
    k_partial<<<dim3(64), dim3(256), 0, stream>>>(ssp, acc, cnt, out);
}